// Round 1
// baseline (123.627 us; speedup 1.0000x reference)
//
#include <hip/hip_runtime.h>

#define H 1024
#define W 1024
#define NIMG 8
#define TX 128
#define CY 16
#define RS_ROWS (CY + 8)          // 24 rowsum rows per chunk
#define NBX (W / TX)              // 8
#define NBY (H / CY)              // 64
#define NBLOCKS (NBX * NBY * NIMG) // 4096
#define EPS 1e-5f

__global__ __launch_bounds__(256, 2)
void ncc_main(const float* __restrict__ I, const float* __restrict__ J,
              float* __restrict__ partial) {
  // rowsum storage: float4 = {sI, sJ, sII, sJJ}, float = sIJ
  __shared__ float4 rs4[RS_ROWS][TX];   // 48 KiB
  __shared__ float  rs1[RS_ROWS][TX];   // 12 KiB
  __shared__ float  red[4];

  const int tid = threadIdx.x;
  const int gx = blockIdx.x, gy = blockIdx.y, n = blockIdx.z;
  const size_t img_off = (size_t)n * H * W;

  // ---------- Phase 1: horizontal 9-box sums of I, J, I^2, J^2, IJ ----------
  // unit u -> (row r in [0,24), xgroup xg in [0,16)); each unit = 8 output px
  for (int u = tid; u < RS_ROWS * 16; u += 256) {
    const int r  = u >> 4;
    const int xg = u & 15;
    const int y  = gy * CY + r - 4;     // global row (zero-pad outside)
    float a[16], b[16];
    if (y >= 0 && y < H) {
      const int xbase = gx * TX + xg * 8 - 4;  // global x of a[0]
      const float* Ip = I + img_off + (size_t)y * W;
      const float* Jp = J + img_off + (size_t)y * W;
      if (xbase >= 0 && xbase + 16 <= W) {
        // interior: 4 aligned float4 loads per array (xbase % 4 == 0)
        const float4* pa = reinterpret_cast<const float4*>(Ip + xbase);
        const float4* pb = reinterpret_cast<const float4*>(Jp + xbase);
        #pragma unroll
        for (int q = 0; q < 4; ++q) {
          float4 va = pa[q], vb = pb[q];
          a[4*q+0] = va.x; a[4*q+1] = va.y; a[4*q+2] = va.z; a[4*q+3] = va.w;
          b[4*q+0] = vb.x; b[4*q+1] = vb.y; b[4*q+2] = vb.z; b[4*q+3] = vb.w;
        }
      } else {
        #pragma unroll
        for (int k = 0; k < 16; ++k) {
          int xx = xbase + k;
          bool in = (xx >= 0) && (xx < W);
          a[k] = in ? Ip[xx] : 0.0f;
          b[k] = in ? Jp[xx] : 0.0f;
        }
      }
    } else {
      #pragma unroll
      for (int k = 0; k < 16; ++k) { a[k] = 0.0f; b[k] = 0.0f; }
    }
    // build window over a[0..8], then slide 7 times
    float sI = 0.f, sJ = 0.f, sII = 0.f, sJJ = 0.f, sIJ = 0.f;
    #pragma unroll
    for (int k = 0; k < 9; ++k) {
      sI  += a[k];        sJ  += b[k];
      sII += a[k] * a[k]; sJJ += b[k] * b[k];
      sIJ += a[k] * b[k];
    }
    const int xg8 = xg * 8;
    const int xm  = xg & 7;
    #pragma unroll
    for (int i = 0; i < 8; ++i) {
      if (i > 0) {
        float an = a[i+8], al = a[i-1], bn = b[i+8], bl = b[i-1];
        sI  += an - al;           sJ  += bn - bl;
        sII += an*an - al*al;     sJJ += bn*bn - bl*bl;
        sIJ += an*bn - al*bl;
      }
      // XOR swizzle so 16 same-row lanes (stride 8 float4s) spread across banks
      const int px = xg8 + (i ^ xm);
      rs4[r][px] = make_float4(sI, sJ, sII, sJJ);
      rs1[r][px] = sIJ;
    }
  }
  __syncthreads();

  // ---------- Phase 2: vertical 9-box + cc ----------
  const int x = tid & 127;        // column in tile
  const int h = tid >> 7;         // row-half: rows [8h, 8h+8)
  const int xs = (x & ~7) | ((x ^ (x >> 3)) & 7);   // un-swizzle, thread-constant
  float4 rows4[9]; float rows1[9];
  float wI = 0.f, wJ = 0.f, wII = 0.f, wJJ = 0.f, wIJ = 0.f;
  #pragma unroll
  for (int k = 0; k < 9; ++k) {
    rows4[k] = rs4[h*8 + k][xs];
    rows1[k] = rs1[h*8 + k][xs];
    wI += rows4[k].x; wJ += rows4[k].y; wII += rows4[k].z; wJJ += rows4[k].w;
    wIJ += rows1[k];
  }
  const float inv81 = 1.0f / 81.0f;
  float acc = 0.f;
  #pragma unroll
  for (int i = 0; i < 8; ++i) {
    if (i > 0) {
      // entering row h*8+8+i; leaving row h*8+i-1 lives in init registers
      float4 e4 = rs4[h*8 + 8 + i][xs];
      float  e1 = rs1[h*8 + 8 + i][xs];
      wI  += e4.x - rows4[i-1].x;  wJ  += e4.y - rows4[i-1].y;
      wII += e4.z - rows4[i-1].z;  wJJ += e4.w - rows4[i-1].w;
      wIJ += e1   - rows1[i-1];
    }
    // cc = cross^2 / (Ivar*Jvar + eps), algebraically equal to reference
    float cross = wIJ - wI * wJ * inv81;
    float Iv    = wII - wI * wI * inv81;
    float Jv    = wJJ - wJ * wJ * inv81;
    acc += cross * cross / (Iv * Jv + EPS);
  }

  // ---------- block reduction -> partial ----------
  #pragma unroll
  for (int off = 32; off > 0; off >>= 1)
    acc += __shfl_down(acc, off, 64);
  if ((tid & 63) == 0) red[tid >> 6] = acc;
  __syncthreads();
  if (tid == 0) {
    const int blin = blockIdx.x + NBX * (blockIdx.y + NBY * (int)blockIdx.z);
    partial[blin] = red[0] + red[1] + red[2] + red[3];
  }
}

__global__ __launch_bounds__(256)
void ncc_reduce(const float* __restrict__ partial, float* __restrict__ out) {
  __shared__ float red[4];
  const int tid = threadIdx.x;
  float s = 0.f;
  #pragma unroll 4
  for (int i = tid; i < NBLOCKS; i += 256) s += partial[i];
  #pragma unroll
  for (int off = 32; off > 0; off >>= 1)
    s += __shfl_down(s, off, 64);
  if ((tid & 63) == 0) red[tid >> 6] = s;
  __syncthreads();
  if (tid == 0)
    out[0] = (red[0] + red[1] + red[2] + red[3]) *
             (1.0f / (float)((size_t)NIMG * H * W));
}

extern "C" void kernel_launch(void* const* d_in, const int* in_sizes, int n_in,
                              void* d_out, int out_size, void* d_ws, size_t ws_size,
                              hipStream_t stream) {
  const float* I = (const float*)d_in[0];
  const float* J = (const float*)d_in[1];
  float* out     = (float*)d_out;
  float* partial = (float*)d_ws;           // needs 4096 * 4 B = 16 KiB

  dim3 grid(NBX, NBY, NIMG);               // 8 x 64 x 8 = 4096 blocks
  hipLaunchKernelGGL(ncc_main, grid, dim3(256), 0, stream, I, J, partial);
  hipLaunchKernelGGL(ncc_reduce, dim3(1), dim3(256), 0, stream, partial, out);
}

// Round 2
// 112.930 us; speedup vs baseline: 1.0947x; 1.0947x over previous
//
#include <hip/hip_runtime.h>

#define H 1024
#define W 1024
#define NIMG 8
#define TX 128
#define CY 8
#define RS_ROWS (CY + 8)            // 16 rowsum rows per chunk
#define NBX (W / TX)                // 8
#define NBY (H / CY)                // 128
#define NBLOCKS (NBX * NBY * NIMG)  // 8192
#define EPS 1e-5f

// LDS: rs4 = 16*128*16 = 32768 B, rs1 = 16*128*4 = 8192 B, total 40960 B
// -> exactly 4 blocks/CU (160 KiB). red[] is folded into rs1 after a barrier.
__global__ __launch_bounds__(256, 4)
void ncc_main(const float* __restrict__ I, const float* __restrict__ J,
              float* __restrict__ partial) {
  __shared__ float4 rs4[RS_ROWS][TX];
  __shared__ float  rs1[RS_ROWS][TX];

  const int tid = threadIdx.x;
  const int gx = blockIdx.x, gy = blockIdx.y, n = blockIdx.z;
  const size_t img_off = (size_t)n * H * W;

  // ---------- Phase 1: horizontal 9-box sums; exactly 1 unit per thread ----
  {
    const int r  = tid >> 4;            // rowsum row 0..15
    const int xg = tid & 15;            // x-group of 8 px
    const int y  = gy * CY + r - 4;     // global row (zero-pad outside)
    float a[16], b[16];
    if (y >= 0 && y < H) {
      const int xbase = gx * TX + xg * 8 - 4;
      const float* Ip = I + img_off + (size_t)y * W;
      const float* Jp = J + img_off + (size_t)y * W;
      if (xbase >= 0 && xbase + 16 <= W) {
        const float4* pa = reinterpret_cast<const float4*>(Ip + xbase);
        const float4* pb = reinterpret_cast<const float4*>(Jp + xbase);
        #pragma unroll
        for (int q = 0; q < 4; ++q) {
          float4 va = pa[q], vb = pb[q];
          a[4*q+0] = va.x; a[4*q+1] = va.y; a[4*q+2] = va.z; a[4*q+3] = va.w;
          b[4*q+0] = vb.x; b[4*q+1] = vb.y; b[4*q+2] = vb.z; b[4*q+3] = vb.w;
        }
      } else {
        #pragma unroll
        for (int k = 0; k < 16; ++k) {
          int xx = xbase + k;
          bool in = (xx >= 0) && (xx < W);
          a[k] = in ? Ip[xx] : 0.0f;
          b[k] = in ? Jp[xx] : 0.0f;
        }
      }
    } else {
      #pragma unroll
      for (int k = 0; k < 16; ++k) { a[k] = 0.0f; b[k] = 0.0f; }
    }
    float sI = 0.f, sJ = 0.f, sII = 0.f, sJJ = 0.f, sIJ = 0.f;
    #pragma unroll
    for (int k = 0; k < 9; ++k) {
      sI  += a[k];        sJ  += b[k];
      sII += a[k] * a[k]; sJJ += b[k] * b[k];
      sIJ += a[k] * b[k];
    }
    const int xg8 = xg * 8;
    const int xm  = xg & 7;
    #pragma unroll
    for (int i = 0; i < 8; ++i) {
      if (i > 0) {
        float an = a[i+8], al = a[i-1], bn = b[i+8], bl = b[i-1];
        sI  += an - al;           sJ  += bn - bl;
        sII += an*an - al*al;     sJJ += bn*bn - bl*bl;
        sIJ += an*bn - al*bl;
      }
      // XOR swizzle: 16 same-row lanes (stride 8 float4s) spread across banks
      const int px = xg8 + (i ^ xm);
      rs4[r][px] = make_float4(sI, sJ, sII, sJJ);
      rs1[r][px] = sIJ;
    }
  }
  __syncthreads();

  // ---------- Phase 2: vertical 9-box + cc; 128 cols x 2 halves x 4 rows ---
  const int x  = tid & 127;
  const int h  = tid >> 7;                          // 0/1 -> rows [4h, 4h+4)
  const int xs = (x & ~7) | ((x ^ (x >> 3)) & 7);   // un-swizzle (const)
  const int base = h * 4;
  float4 rows4[9]; float rows1[9];
  float wI = 0.f, wJ = 0.f, wII = 0.f, wJJ = 0.f, wIJ = 0.f;
  #pragma unroll
  for (int k = 0; k < 9; ++k) {
    rows4[k] = rs4[base + k][xs];
    rows1[k] = rs1[base + k][xs];
    wI += rows4[k].x; wJ += rows4[k].y; wII += rows4[k].z; wJJ += rows4[k].w;
    wIJ += rows1[k];
  }
  const float inv81 = 1.0f / 81.0f;
  float acc = 0.f;
  #pragma unroll
  for (int i = 0; i < 4; ++i) {
    if (i > 0) {
      float4 e4 = rs4[base + 8 + i][xs];
      float  e1 = rs1[base + 8 + i][xs];
      wI  += e4.x - rows4[i-1].x;  wJ  += e4.y - rows4[i-1].y;
      wII += e4.z - rows4[i-1].z;  wJJ += e4.w - rows4[i-1].w;
      wIJ += e1   - rows1[i-1];
    }
    float cross = wIJ - wI * wJ * inv81;
    float Iv    = wII - wI * wI * inv81;
    float Jv    = wJJ - wJ * wJ * inv81;
    acc += cross * cross / (Iv * Jv + EPS);
  }

  // ---------- block reduction -> partial (reuse rs1 as scratch) ----------
  #pragma unroll
  for (int off = 32; off > 0; off >>= 1)
    acc += __shfl_down(acc, off, 64);
  __syncthreads();                       // all rs reads done before reuse
  if ((tid & 63) == 0) rs1[0][tid >> 6] = acc;
  __syncthreads();
  if (tid == 0) {
    const int blin = blockIdx.x + NBX * (blockIdx.y + NBY * (int)blockIdx.z);
    partial[blin] = rs1[0][0] + rs1[0][1] + rs1[0][2] + rs1[0][3];
  }
}

__global__ __launch_bounds__(256)
void ncc_reduce(const float* __restrict__ partial, float* __restrict__ out) {
  __shared__ float red[4];
  const int tid = threadIdx.x;
  float s = 0.f;
  #pragma unroll 8
  for (int i = tid; i < NBLOCKS; i += 256) s += partial[i];
  #pragma unroll
  for (int off = 32; off > 0; off >>= 1)
    s += __shfl_down(s, off, 64);
  if ((tid & 63) == 0) red[tid >> 6] = s;
  __syncthreads();
  if (tid == 0)
    out[0] = (red[0] + red[1] + red[2] + red[3]) *
             (1.0f / (float)((size_t)NIMG * H * W));
}

extern "C" void kernel_launch(void* const* d_in, const int* in_sizes, int n_in,
                              void* d_out, int out_size, void* d_ws, size_t ws_size,
                              hipStream_t stream) {
  const float* I = (const float*)d_in[0];
  const float* J = (const float*)d_in[1];
  float* out     = (float*)d_out;
  float* partial = (float*)d_ws;            // 8192 * 4 B = 32 KiB scratch

  dim3 grid(NBX, NBY, NIMG);                // 8 x 128 x 8 = 8192 blocks
  hipLaunchKernelGGL(ncc_main, grid, dim3(256), 0, stream, I, J, partial);
  hipLaunchKernelGGL(ncc_reduce, dim3(1), dim3(256), 0, stream, partial, out);
}